// Round 17
// baseline (467.307 us; speedup 1.0000x reference)
//
#include <hip/hip_runtime.h>

#define NB 32
#define NC 512
#define NH 56
#define NW 56
#define HW 3136       // 56*56
#define CHW 1605632   // 512*3136
#define CPB 8         // planes (channels) per block in k12
#define NPART 64      // NC/CPB partial chunks

// ---- K12: fused mask + channel max/sum partials. CPB=8 -> 2048 blocks
// (8/CU) for 2x in-flight loads vs the 449µs CPB=16 config; double-buffered
// LDS reduce slots (one barrier per plane). No atomics: private partials
// written coalesced to d_out scratch; k2bb reduces ascending-chunk.
__global__ __launch_bounds__(256) void k12_maskbb(const float* __restrict__ x,
                                                  float* __restrict__ mask,
                                                  float* __restrict__ pmax,
                                                  double* __restrict__ psum) {
    const int b = blockIdx.x >> 6;      // grid = 32*64
    const int ch = blockIdx.x & 63;
    const int c0 = ch * CPB;
    const int tid = threadIdx.x;
    __shared__ double rsum[2][4];       // [p&1][wave]
    __shared__ float rmax[2][4];
    const bool has4 = (tid < 16);       // 784 float4s = 3*256 + 16
    float am[16];
    double as[16];
#pragma unroll
    for (int k = 0; k < 16; k++) { am[k] = 0.f; as[k] = 0.0; }

    for (int p = 0; p < CPB; p++) {
        const float4* px = (const float4*)(x + (size_t)(b * NC + c0 + p) * HW);
        float v[16];
#pragma unroll
        for (int k = 0; k < 4; k++) {
            if (k < 3 || has4) {
                float4 t = px[tid + k * 256];
                v[4 * k + 0] = fmaxf(t.x, 0.f);
                v[4 * k + 1] = fmaxf(t.y, 0.f);
                v[4 * k + 2] = fmaxf(t.z, 0.f);
                v[4 * k + 3] = fmaxf(t.w, 0.f);
            } else {
                v[4 * k + 0] = 0.f; v[4 * k + 1] = 0.f;
                v[4 * k + 2] = 0.f; v[4 * k + 3] = 0.f;
            }
        }
        // per-thread reduce in the same order as the verified chain
        float lmax = 0.f;
        double lsum = 0.0;
#pragma unroll
        for (int k = 0; k < 16; k++) {
            lmax = fmaxf(lmax, v[k]);
            lsum += (double)v[k];
        }
        for (int off = 32; off; off >>= 1) {
            lsum += __shfl_xor(lsum, off);
            lmax = fmaxf(lmax, __shfl_xor(lmax, off));
        }
        const int slot = p & 1;
        if ((tid & 63) == 0) { rsum[slot][tid >> 6] = lsum; rmax[slot][tid >> 6] = lmax; }
        __syncthreads();
        // safe: iteration p+1 writes slot^1; this slot is rewritten at p+2,
        // unreachable before every thread passes the p+1 barrier.
        double s = rsum[slot][0] + rsum[slot][1] + rsum[slot][2] + rsum[slot][3];
        float m = fmaxf(fmaxf(rmax[slot][0], rmax[slot][1]),
                        fmaxf(rmax[slot][2], rmax[slot][3]));
        float avg = (float)(s / 3136.0);
        float mk = ((m - avg) < 0.5f) ? 0.f : 1.f;
        if (tid == 0) mask[b * NC + c0 + p] = mk;
        if (mk != 0.f) {
#pragma unroll
            for (int k = 0; k < 16; k++) {
                am[k] = fmaxf(am[k], v[k]);
                as[k] += (double)v[k];
            }
        }
    }
    // coalesced private-partial writeout (no atomics)
    const size_t pb = ((size_t)ch * NB + b) * HW;
#pragma unroll
    for (int k = 0; k < 4; k++) {
        if (k < 3 || has4) {
            const int pos = 4 * (tid + k * 256);
            *(float4*)(pmax + pb + pos) =
                make_float4(am[4 * k], am[4 * k + 1], am[4 * k + 2], am[4 * k + 3]);
            *(double2*)(psum + pb + pos)     = make_double2(as[4 * k],     as[4 * k + 1]);
            *(double2*)(psum + pb + pos + 2) = make_double2(as[4 * k + 2], as[4 * k + 3]);
        }
    }
}

// ---- K2bb: reduce chunk partials (deterministic ascending order) -> bb ----
__global__ __launch_bounds__(256) void k2bb_fin(const float* __restrict__ pmax,
                                                const double* __restrict__ psum,
                                                float* __restrict__ bb) {
    const int i = blockIdx.x * 256 + threadIdx.x;  // grid*block == NB*HW exactly
    const int b = i / HW, pos = i % HW;
    float m = 0.f;
    double s = 0.0;
#pragma unroll 4
    for (int ch = 0; ch < NPART; ch++) {
        const size_t idx = ((size_t)ch * NB + b) * HW + pos;
        m = fmaxf(m, pmax[idx]);
        s += psum[idx];
    }
    double cmean = s * (1.0 / 512.0);
    double d = fabs((double)m - cmean);
    bb[i] = (float)(1.0 - exp(-d));
}

// ---- K2b: per-(b,c) plane: x_max and pooled of x2 = bb*x1 (one block) ----
__global__ __launch_bounds__(256) void k2b_stats(const float* __restrict__ x,
                                                 const float* __restrict__ mask,
                                                 const float* __restrict__ bb,
                                                 float* __restrict__ xmax,
                                                 float* __restrict__ pooled) {
    const int plane = blockIdx.x;  // b*512 + c
    const int b = plane >> 9;
    const float4* px = (const float4*)(x + (size_t)plane * HW);
    const float4* pbb = (const float4*)(bb + (size_t)b * HW);
    const float mk = mask[plane];
    float m = 0.f;
    double s = 0.0;
    for (int i = threadIdx.x; i < HW / 4; i += 256) {
        float4 v = px[i];
        float4 bv = pbb[i];
        float x0 = fmaxf(v.x, 0.f) * mk * bv.x;  // identical fp32 chain as K4
        float x1 = fmaxf(v.y, 0.f) * mk * bv.y;
        float x2 = fmaxf(v.z, 0.f) * mk * bv.z;
        float x3 = fmaxf(v.w, 0.f) * mk * bv.w;
        m = fmaxf(m, fmaxf(fmaxf(x0, x1), fmaxf(x2, x3)));
        s += (double)x0 + (double)x1 + (double)x2 + (double)x3;
    }
    for (int off = 32; off; off >>= 1) {
        s += __shfl_xor(s, off);
        m = fmaxf(m, __shfl_xor(m, off));
    }
    __shared__ double ssum[4];
    __shared__ float smax[4];
    int wid = threadIdx.x >> 6, lane = threadIdx.x & 63;
    if (lane == 0) { ssum[wid] = s; smax[wid] = m; }
    __syncthreads();
    if (threadIdx.x == 0) {
        double st = ssum[0] + ssum[1] + ssum[2] + ssum[3];
        float mt = fmaxf(fmaxf(smax[0], smax[1]), fmaxf(smax[2], smax[3]));
        xmax[plane] = mt;
        pooled[plane] = (float)(st / 3136.0);
    }
}

// ------------- K3: FC gates (wave-per-output dot products) -> thres -------------
__global__ __launch_bounds__(256) void k3_gates(const float* __restrict__ pooled,
                                                const float* __restrict__ W1,
                                                const float* __restrict__ W3,
                                                const float* __restrict__ xmax,
                                                float* __restrict__ thres) {
    int wave = threadIdx.x >> 6, lane = threadIdx.x & 63;
    int task0 = (blockIdx.x * 4 + wave) * 4;
    for (int t = 0; t < 4; t++) {
        int task = task0 + t;                       // b*512 + j
        int b = task >> 9, j = task & 511;
        const float* r1 = W1 + j * 512;
        const float* r3 = W3 + j * 512;
        const float* pr = pooled + b * 512;
        double s1 = 0.0, s3 = 0.0;
        for (int k = lane; k < 512; k += 64) {
            double p = (double)pr[k];
            s1 += p * (double)r1[k];
            s3 += p * (double)r3[k];
        }
        for (int off = 32; off; off >>= 1) {
            s1 += __shfl_xor(s1, off);
            s3 += __shfl_xor(s3, off);
        }
        if (lane == 0) {
            float c1 = (float)(1.0 / (1.0 + exp(-s1)));   // sigmoid
            double r = s3 > 0.0 ? s3 : 0.0;               // relu
            float c3 = (float)((r < 1.0) ? 1.2 : r);
            thres[task] = c1 * c3 * xmax[task];           // np's fp32 mul order
        }
    }
}

// ---------------- K4: recompute x2, threshold, write fp32 out ----------------
__global__ __launch_bounds__(256) void k4_out(const float* __restrict__ x,
                                              const float* __restrict__ mask,
                                              const float* __restrict__ bb,
                                              const float* __restrict__ thres,
                                              float* __restrict__ out) {
    const int plane = blockIdx.x;
    const int b = plane >> 9;
    const float4* px = (const float4*)(x + (size_t)plane * HW);
    float4* po = (float4*)(out + (size_t)plane * HW);
    const float4* pbb = (const float4*)(bb + (size_t)b * HW);
    const float th = thres[plane];
    const float mk = mask[plane];
    for (int i = threadIdx.x; i < HW / 4; i += 256) {
        float4 v = px[i];
        float4 bv = pbb[i];
        float x0 = fmaxf(v.x, 0.f) * mk * bv.x;  // identical fp32 chain as K2b
        float x1 = fmaxf(v.y, 0.f) * mk * bv.y;
        float x2 = fmaxf(v.z, 0.f) * mk * bv.z;
        float x3 = fmaxf(v.w, 0.f) * mk * bv.w;
        float4 o;
        o.x = (x0 < th) ? 0.f : x0;
        o.y = (x1 < th) ? 0.f : x1;
        o.z = (x2 < th) ? 0.f : x2;
        o.w = (x3 < th) ? 0.f : x3;
        po[i] = o;
    }
}

extern "C" void kernel_launch(void* const* d_in, const int* in_sizes, int n_in,
                              void* d_out, int out_size, void* d_ws, size_t ws_size,
                              hipStream_t stream) {
    const float* x  = (const float*)d_in[0];
    const float* W1 = (const float*)d_in[1];
    const float* W3 = (const float*)d_in[2];
    float* out = (float*)d_out;
    float* ws = (float*)d_ws;
    // ws layout (float slots) — same verified 648 KB footprint:
    //   bb     : [0, 100352)
    //   mask   : [100352, 116736)
    //   xmax   : [116736, 133120)
    //   pooled : [133120, 149504)
    //   thres  : [149504, 165888)   total 663,552 B
    float* bb     = ws;
    float* mask   = ws + 100352;
    float* xmax   = ws + 116736;
    float* pooled = ws + 133120;
    float* thres  = ws + 149504;
    // chunk partials in d_out scratch (77 MB of 205 MB), consumed by k2bb
    // strictly before k4 overwrites d_out with the real output:
    //   psum : NPART*NB*HW doubles at offset 0        (51,380,224 B)
    //   pmax : NPART*NB*HW floats  after psum         (25,690,112 B)
    double* psum = (double*)d_out;
    float* pmax  = (float*)d_out + (size_t)NPART * NB * HW * 2;  // *2: f64->f32 slots

    hipLaunchKernelGGL(k12_maskbb, dim3(NB * NPART),    dim3(256), 0, stream,
                       x, mask, pmax, psum);
    hipLaunchKernelGGL(k2bb_fin,   dim3(NB * HW / 256), dim3(256), 0, stream,
                       pmax, psum, bb);
    hipLaunchKernelGGL(k2b_stats,  dim3(NB * NC), dim3(256), 0, stream,
                       x, mask, bb, xmax, pooled);
    hipLaunchKernelGGL(k3_gates,   dim3(1024),    dim3(256), 0, stream,
                       pooled, W1, W3, xmax, thres);
    hipLaunchKernelGGL(k4_out,     dim3(NB * NC), dim3(256), 0, stream,
                       x, mask, bb, thres, out);
}